// Round 1
// baseline (170.877 us; speedup 1.0000x reference)
//
#include <hip/hip_runtime.h>
#include <hip/hip_bf16.h>
#include <math.h>

#define IH 48
#define IW 48
#define NN 2304          // N = IH*IW
#define CC 256           // channels
#define NH 8
#define HD 32
#define HID 1024
#define NBIAS 9025       // (2*48-1)^2
#define SCALE 0.17677669529663687f
#define LOG2E 1.4426950408889634f
#define LN_EPS 1e-5f

typedef __attribute__((ext_vector_type(8))) short bf16x8;   // 8 bf16 in 4 VGPRs
typedef __attribute__((ext_vector_type(4))) float f32x4;

__device__ __forceinline__ short f2b(float f) {
    __hip_bfloat16 h = __float2bfloat16(f);
    short s; __builtin_memcpy(&s, &h, 2); return s;
}
__device__ __forceinline__ float b2f(short s) {
    __hip_bfloat16 h; __builtin_memcpy(&h, &s, 2); return __bfloat162float(h);
}
__device__ __forceinline__ float fast_exp2(float x) {
#if __has_builtin(__builtin_amdgcn_exp2f)
    return __builtin_amdgcn_exp2f(x);     // single v_exp_f32
#else
    return exp2f(x);
#endif
}

// ------- Prep: ln1 (blocks 0..NN-1) + x2 prefill + weight/bias bf16 conv ---
// bias table is pre-multiplied by LOG2E so attention can use exp2 directly.
__global__ void prep_kernel(const float* __restrict__ x, const float* __restrict__ g,
                            const float* __restrict__ b, const float* __restrict__ bp,
                            short* __restrict__ t1, float* __restrict__ x2,
                            const float* __restrict__ w_qkv, const float* __restrict__ w_proj,
                            const float* __restrict__ w_fc1, const float* __restrict__ w_fc2,
                            const float* __restrict__ bt,
                            short* __restrict__ o_qkv, short* __restrict__ o_proj,
                            short* __restrict__ o_fc1, short* __restrict__ o_fc2,
                            short* __restrict__ o_bias)
{
    const int bid = blockIdx.x, tid = threadIdx.x;
    if (bid < NN) {        // ---- LayerNorm row + residual/bias prefill ----
        __shared__ float red[8];
        float v = x[bid * CC + tid];
        float s = v, s2 = v * v;
        #pragma unroll
        for (int off = 32; off > 0; off >>= 1) {
            s  += __shfl_xor(s, off);
            s2 += __shfl_xor(s2, off);
        }
        const int wid = tid >> 6;
        if ((tid & 63) == 0) { red[wid * 2] = s; red[wid * 2 + 1] = s2; }
        __syncthreads();
        float tot  = red[0] + red[2] + red[4] + red[6];
        float tot2 = red[1] + red[3] + red[5] + red[7];
        float mu   = tot * (1.0f / CC);
        float var  = tot2 * (1.0f / CC) - mu * mu;
        float rstd = rsqrtf(var + LN_EPS);
        t1[bid * CC + tid] = f2b((v - mu) * rstd * g[tid] + b[tid]);
        x2[bid * CC + tid] = v + bp[tid];     // proj epilogue base (split-K atomics)
        return;
    }
    // ---- weight conversions, flat grid-stride over 858632 elements ----
    const int stride = (gridDim.x - NN) * 256;
    for (int i = (bid - NN) * 256 + tid; i < 858632; i += stride) {
        int j = i;
        if (j < 196608)            { int n = j >> 8,  k = j & 255;  o_qkv [j] = f2b(w_qkv [k * 768  + n]); }
        else if ((j -= 196608) < 65536)  { int n = j >> 8,  k = j & 255;  o_proj[j] = f2b(w_proj[k * 256  + n]); }
        else if ((j -= 65536)  < 262144) { int n = j >> 8,  k = j & 255;  o_fc1 [j] = f2b(w_fc1 [k * 1024 + n]); }
        else if ((j -= 262144) < 262144) { int n = j >> 10, k = j & 1023; o_fc2 [j] = f2b(w_fc2 [k * 256  + n]); }
        else { j -= 262144; int h = j / NBIAS, idx = j - h * NBIAS; o_bias[j] = f2b(bt[idx * NH + h] * LOG2E); }
    }
}

// ---------------- LayerNorm (ln2) + fc2 epilogue base prefill --------------
__global__ void ln_kernel(const float* __restrict__ x,
                          const float* __restrict__ g,
                          const float* __restrict__ b,
                          const float* __restrict__ bfc2,
                          short* __restrict__ out_t,
                          float* __restrict__ out_base)
{
    __shared__ float red[8];
    const int row = blockIdx.x, tid = threadIdx.x;
    float v = x[row * CC + tid];
    float s = v, s2 = v * v;
    #pragma unroll
    for (int off = 32; off > 0; off >>= 1) {
        s  += __shfl_xor(s, off);
        s2 += __shfl_xor(s2, off);
    }
    const int wid = tid >> 6;
    if ((tid & 63) == 0) { red[wid * 2] = s; red[wid * 2 + 1] = s2; }
    __syncthreads();
    float tot  = red[0] + red[2] + red[4] + red[6];
    float tot2 = red[1] + red[3] + red[5] + red[7];
    float mu   = tot * (1.0f / CC);
    float var  = tot2 * (1.0f / CC) - mu * mu;
    float rstd = rsqrtf(var + LN_EPS);
    out_t[row * CC + tid] = f2b((v - mu) * rstd * g[tid] + b[tid]);
    out_base[row * CC + tid] = v + bfc2[tid];  // fc2 epilogue base (split-K atomics)
}

// --- MFMA GEMM core: 64x64 tile, 4 waves, K-step 64, register-pipelined ----
// KLEN = K range this block covers (starting at kb), KSTR = row stride of A/BT.
#define GSTRIDE 72
template<int KLEN, int KSTR>
__device__ __forceinline__ void mfma_gemm_core(const short* __restrict__ A,
                                               const short* __restrict__ BT,
                                               int m0, int n0, int kb, f32x4 acc[4],
                                               short* lds)
{
    short* As = lds;                 // [64][72]
    short* Bs = lds + 64 * GSTRIDE;  // [64][72]
    const int tid  = threadIdx.x;
    const int w    = tid >> 6, lane = tid & 63;
    const int quad = lane >> 4, l15 = lane & 15;
    const int sr = tid >> 2;            // staging row 0..63
    const int sc = (tid & 3) * 16;      // k-granule 0,16,32,48
    #pragma unroll
    for (int c = 0; c < 4; ++c) acc[c] = (f32x4){0.f, 0.f, 0.f, 0.f};

    const short* Ap = &A [(m0 + sr) * KSTR + kb + sc];
    const short* Bp = &BT[(n0 + sr) * KSTR + kb + sc];
    bf16x8 ra0 = *(const bf16x8*)Ap,       ra1 = *(const bf16x8*)(Ap + 8);
    bf16x8 rb0 = *(const bf16x8*)Bp,       rb1 = *(const bf16x8*)(Bp + 8);

    for (int k0 = 0; k0 < KLEN; k0 += 64) {
        __syncthreads();                       // LDS consumers of tile k-1 done
        *(bf16x8*)&As[sr * GSTRIDE + sc]     = ra0;
        *(bf16x8*)&As[sr * GSTRIDE + sc + 8] = ra1;
        *(bf16x8*)&Bs[sr * GSTRIDE + sc]     = rb0;
        *(bf16x8*)&Bs[sr * GSTRIDE + sc + 8] = rb1;
        if (k0 + 64 < KLEN) {                  // prefetch tile k+1 (overlaps below)
            ra0 = *(const bf16x8*)(Ap + k0 + 64);
            ra1 = *(const bf16x8*)(Ap + k0 + 72);
            rb0 = *(const bf16x8*)(Bp + k0 + 64);
            rb1 = *(const bf16x8*)(Bp + k0 + 72);
        }
        __syncthreads();                       // tile k visible
        #pragma unroll
        for (int s = 0; s < 2; ++s) {
            bf16x8 a = *(const bf16x8*)&As[(w * 16 + l15) * GSTRIDE + s * 32 + quad * 8];
            #pragma unroll
            for (int c = 0; c < 4; ++c) {
                bf16x8 b = *(const bf16x8*)&Bs[(c * 16 + l15) * GSTRIDE + s * 32 + quad * 8];
                acc[c] = __builtin_amdgcn_mfma_f32_16x16x32_bf16(a, b, acc[c], 0, 0, 0);
            }
        }
    }
}
// C/D layout [m89]: col = n-tile*16 + (lane&15), row = 16w + quad*4 + reg.

// ---------------- QKV: t1 @ w_qkvT -> qb, kb (bf16 [h][n][d]), vT [h][d][n]-
// q is pre-scaled by SCALE*LOG2E so attention softmax can use exp2 directly.
__global__ void qkv_kernel(const short* __restrict__ t1, const short* __restrict__ wT,
                           short* __restrict__ qb, short* __restrict__ kb,
                           short* __restrict__ vT)
{
    __shared__ short lds[2 * 64 * GSTRIDE];
    f32x4 acc[4];
    const int m0 = blockIdx.y * 64, n0 = blockIdx.x * 64;
    mfma_gemm_core<256, 256>(t1, wT, m0, n0, 0, acc, lds);
    const int lane = threadIdx.x & 63, w = threadIdx.x >> 6;
    const int quad = lane >> 4, l15 = lane & 15;
    #pragma unroll
    for (int c = 0; c < 4; ++c) {
        int col = n0 + c * 16 + l15;
        int three = col >> 8, rem = col & 255;
        int h = rem >> 5, d = rem & 31;
        #pragma unroll
        for (int r = 0; r < 4; ++r) {
            int row = m0 + w * 16 + quad * 4 + r;
            float v = acc[c][r];
            if (three == 0)      qb[(h * NN + row) * HD + d] = f2b(v * (SCALE * LOG2E));
            else if (three == 1) kb[(h * NN + row) * HD + d] = f2b(v);
            else                 vT[(h * HD + d) * NN + row] = f2b(v);
        }
    }
}

// -------- MFMA flash attention: block=(head,16q), 4 waves x 576 keys -------
// 4-wave blocks -> 13.8 KB LDS -> 8 blocks/CU resident -> all 1152 blocks
// co-resident in one round (no ragged 2nd round; 4.5 waves/SIMD throughout).
#define PSTRIDE 40    // sbuf row stride: 80 B (16B-aligned, conflict-free b128)
__global__ __launch_bounds__(256) void attn_kernel(
        const short* __restrict__ qb, const short* __restrict__ kb,
        const short* __restrict__ vT, const short* __restrict__ biasT,
        short* __restrict__ o)
{
    __shared__ float Ored[4][16][33];
    __shared__ float lred[4][16];
    __shared__ short sbuf[4][16 * PSTRIDE];
    const int w = threadIdx.x >> 6, lane = threadIdx.x & 63;
    const int quad = lane >> 4, l15 = lane & 15;
    const int h = blockIdx.x / 144, q0 = (blockIdx.x % 144) * 16;
    const int t0 = w * 576;
    short* sb = &sbuf[w][0];
    const short* bt = &biasT[h * NBIAS];

    // Q fragment: A[m=lane&15][k=quad*8+j]  (q pre-scaled by SCALE*LOG2E)
    bf16x8 qf = *(const bf16x8*)&qb[(h * NN + q0 + l15) * HD + quad * 8];

    int base[4];
    #pragma unroll
    for (int r = 0; r < 4; ++r) {
        int row = q0 + quad * 4 + r;
        int qi = row / IW, qj = row % IW;
        base[r] = (qi + 47) * 95 + (qj + 47);
    }

    f32x4 O0 = (f32x4){0.f,0.f,0.f,0.f}, O1 = (f32x4){0.f,0.f,0.f,0.f};
    float lp[4] = {0.f, 0.f, 0.f, 0.f};
    const f32x4 zero = (f32x4){0.f,0.f,0.f,0.f};

    for (int c = 0; c < 18; ++c) {
        const int t = t0 + c * 32;
        bf16x8 k0f = *(const bf16x8*)&kb[(h * NN + t      + l15) * HD + quad * 8];
        bf16x8 k1f = *(const bf16x8*)&kb[(h * NN + t + 16 + l15) * HD + quad * 8];
        f32x4 s0 = __builtin_amdgcn_mfma_f32_16x16x32_bf16(qf, k0f, zero, 0, 0, 0);
        f32x4 s1 = __builtin_amdgcn_mfma_f32_16x16x32_bf16(qf, k1f, zero, 0, 0, 0);
        bf16x8 v0 = *(const bf16x8*)&vT[(h * HD + l15)      * NN + t + quad * 8];
        bf16x8 v1 = *(const bf16x8*)&vT[(h * HD + 16 + l15) * NN + t + quad * 8];

        int key0 = t + l15, key1 = t + 16 + l15;
        int boff0 = -((key0 / IW) * 95 + key0 % IW);
        int boff1 = -((key1 / IW) * 95 + key1 % IW);

        #pragma unroll
        for (int r = 0; r < 4; ++r) {
            float p0 = fast_exp2(s0[r] + b2f(bt[base[r] + boff0]));
            float p1 = fast_exp2(s1[r] + b2f(bt[base[r] + boff1]));
            lp[r] += p0 + p1;
            sb[(quad * 4 + r) * PSTRIDE + l15]      = f2b(p0);
            sb[(quad * 4 + r) * PSTRIDE + 16 + l15] = f2b(p1);
        }
        // Per-wave private LDS round-trip; DS pipe is in-order within a wave.
        asm volatile("s_waitcnt lgkmcnt(0)" ::: "memory");
        bf16x8 pa = *(const bf16x8*)&sb[l15 * PSTRIDE + quad * 8];
        O0 = __builtin_amdgcn_mfma_f32_16x16x32_bf16(pa, v0, O0, 0, 0, 0);
        O1 = __builtin_amdgcn_mfma_f32_16x16x32_bf16(pa, v1, O1, 0, 0, 0);
    }

    #pragma unroll
    for (int r = 0; r < 4; ++r) {
        float l = lp[r];
        l += __shfl_xor(l, 1); l += __shfl_xor(l, 2);
        l += __shfl_xor(l, 4); l += __shfl_xor(l, 8);
        if (l15 == 0) lred[w][quad * 4 + r] = l;
        Ored[w][quad * 4 + r][l15]      = O0[r];
        Ored[w][quad * 4 + r][16 + l15] = O1[r];
    }
    __syncthreads();
    {   // 256 threads combine 16 q-rows x 32 dims (2 rows per thread)
        const int col = threadIdx.x & 31;
        for (int rr = threadIdx.x >> 5; rr < 16; rr += 8) {
            float s = 0.f, l = 0.f;
            #pragma unroll
            for (int p = 0; p < 4; ++p) { s += Ored[p][rr][col]; l += lred[p][rr]; }
            o[(q0 + rr) * CC + h * HD + col] = f2b(s / l);
        }
    }
}

// ---------------- proj: o @ w_projT -> atomicAdd into x2 (split-K 2) ------
// x2 was prefilled with x + b_proj by prep_kernel.
__global__ void proj_kernel(const short* __restrict__ o, const short* __restrict__ wT,
                            float* __restrict__ x2)
{
    __shared__ short lds[2 * 64 * GSTRIDE];
    f32x4 acc[4];
    const int m0 = blockIdx.y * 64, n0 = blockIdx.x * 64, kb = blockIdx.z * 128;
    mfma_gemm_core<128, 256>(o, wT, m0, n0, kb, acc, lds);
    const int lane = threadIdx.x & 63, w = threadIdx.x >> 6;
    const int quad = lane >> 4, l15 = lane & 15;
    #pragma unroll
    for (int c = 0; c < 4; ++c) {
        int col = n0 + c * 16 + l15;
        #pragma unroll
        for (int r = 0; r < 4; ++r) {
            int row = m0 + w * 16 + quad * 4 + r;
            atomicAdd(&x2[row * CC + col], acc[c][r]);
        }
    }
}

// ---------------- fc1: t2 @ w_fc1T + b_fc1, GELU -> h1 (bf16) --------------
__global__ void fc1_kernel(const short* __restrict__ t2, const short* __restrict__ wT,
                           const float* __restrict__ bias, short* __restrict__ h1)
{
    __shared__ short lds[2 * 64 * GSTRIDE];
    f32x4 acc[4];
    const int m0 = blockIdx.y * 64, n0 = blockIdx.x * 64;
    mfma_gemm_core<256, 256>(t2, wT, m0, n0, 0, acc, lds);
    const int lane = threadIdx.x & 63, w = threadIdx.x >> 6;
    const int quad = lane >> 4, l15 = lane & 15;
    #pragma unroll
    for (int c = 0; c < 4; ++c) {
        int col = n0 + c * 16 + l15;
        #pragma unroll
        for (int r = 0; r < 4; ++r) {
            int row = m0 + w * 16 + quad * 4 + r;
            float v = acc[c][r] + bias[col];
            float ge = 0.5f * v * (1.0f + erff(v * 0.7071067811865476f));
            h1[row * HID + col] = f2b(ge);
        }
    }
}

// ---------------- fc2: h1 @ w_fc2T -> atomicAdd into out (split-K 2) -------
// out was prefilled with x2 + b_fc2 by ln_kernel.
__global__ void fc2_kernel(const short* __restrict__ h1, const short* __restrict__ wT,
                           float* __restrict__ out)
{
    __shared__ short lds[2 * 64 * GSTRIDE];
    f32x4 acc[4];
    const int m0 = blockIdx.y * 64, n0 = blockIdx.x * 64, kb = blockIdx.z * 512;
    mfma_gemm_core<512, 1024>(h1, wT, m0, n0, kb, acc, lds);
    const int lane = threadIdx.x & 63, w = threadIdx.x >> 6;
    const int quad = lane >> 4, l15 = lane & 15;
    #pragma unroll
    for (int c = 0; c < 4; ++c) {
        int col = n0 + c * 16 + l15;
        #pragma unroll
        for (int r = 0; r < 4; ++r) {
            int row = m0 + w * 16 + quad * 4 + r;
            atomicAdd(&out[row * CC + col], acc[c][r]);
        }
    }
}

extern "C" void kernel_launch(void* const* d_in, const int* in_sizes, int n_in,
                              void* d_out, int out_size, void* d_ws, size_t ws_size,
                              hipStream_t stream)
{
    const float* x          = (const float*)d_in[0];
    const float* gamma1     = (const float*)d_in[1];
    const float* beta1      = (const float*)d_in[2];
    const float* w_qkv      = (const float*)d_in[3];
    const float* w_proj     = (const float*)d_in[4];
    const float* b_proj     = (const float*)d_in[5];
    const float* bias_table = (const float*)d_in[6];
    const float* gamma2     = (const float*)d_in[7];
    const float* beta2      = (const float*)d_in[8];
    const float* w_fc1      = (const float*)d_in[9];
    const float* b_fc1      = (const float*)d_in[10];
    const float* w_fc2      = (const float*)d_in[11];
    const float* b_fc2      = (const float*)d_in[12];
    // d_in[13] = rel_idx (int32) — unused: bias index computed analytically.

    short* S = (short*)d_ws;
    const int NC = NN * CC;               // 589824
    short* t1     = S;                    // bf16 [N][C]
    short* qb     = t1  + NC;             // bf16 [h][n][d]
    short* kb     = qb  + NC;             // bf16 [h][n][d]
    short* vT     = kb  + NC;             // bf16 [h][d][n]
    short* obuf   = vT  + NC;             // bf16 [N][C]
    short* t2     = obuf+ NC;             // bf16 [N][C]
    short* h1     = t2  + NC;             // bf16 [N][HID]
    short* wTqkv  = h1  + NN * HID;       // bf16 [768][256]
    short* wTproj = wTqkv  + 768 * 256;   // bf16 [256][256]
    short* wTfc1  = wTproj + 256 * 256;   // bf16 [1024][256]
    short* wTfc2  = wTfc1  + 1024 * 256;  // bf16 [256][1024]
    short* biasT  = wTfc2  + 256 * 1024;  // bf16 [NH][9025] (pre-scaled by LOG2E)
    float* x2     = (float*)(biasT + NH * NBIAS + 8);  // fp32 [N][C]

    prep_kernel<<<NN + 512, 256, 0, stream>>>(x, gamma1, beta1, b_proj, t1, x2,
                                              w_qkv, w_proj, w_fc1, w_fc2, bias_table,
                                              wTqkv, wTproj, wTfc1, wTfc2, biasT);
    qkv_kernel<<<dim3(12, 36), 256, 0, stream>>>(t1, wTqkv, qb, kb, vT);
    attn_kernel<<<1152, 256, 0, stream>>>(qb, kb, vT, biasT, obuf);
    proj_kernel<<<dim3(4, 36, 2), 256, 0, stream>>>(obuf, wTproj, x2);
    ln_kernel<<<NN, 256, 0, stream>>>(x2, gamma2, beta2, b_fc2, t2, (float*)d_out);
    fc1_kernel<<<dim3(16, 36), 256, 0, stream>>>(t2, wTfc1, b_fc1, h1);
    fc2_kernel<<<dim3(4, 36, 2), 256, 0, stream>>>(h1, wTfc2, (float*)d_out);
}